// Round 9
// baseline (616.002 us; speedup 1.0000x reference)
//
#include <hip/hip_runtime.h>
#include <math.h>

#define NN 40000
#define NE 640000
#define NG 64
#define DINV 64
#define HDV 128
#define DEV 16
#define EF (NE + NN)
#define PSPLIT 16

typedef float v2f __attribute__((ext_vector_type(2)));

// channel c <-> position pos(c)=2*(c&63)+(c>>6); position p <-> channel chan(p)=(p>>1)+64*(p&1)
__device__ __forceinline__ int chan_of_pos(int p) { return (p >> 1) + 64 * (p & 1); }

// ---------------- DPP wave-64 sum (rocPRIM sequence), result uniform ----------------
template <int CTRL>
__device__ __forceinline__ float dpp_mov_f(float x) {
    return __builtin_bit_cast(float,
        __builtin_amdgcn_update_dpp(0, __builtin_bit_cast(int, x), CTRL, 0xf, 0xf, true));
}
__device__ __forceinline__ float wave_sum64(float x) {
    x += dpp_mov_f<0x111>(x);   // row_shr:1
    x += dpp_mov_f<0x112>(x);   // row_shr:2
    x += dpp_mov_f<0x114>(x);   // row_shr:4
    x += dpp_mov_f<0x118>(x);   // row_shr:8
    x += dpp_mov_f<0x142>(x);   // row_bcast:15
    x += dpp_mov_f<0x143>(x);   // row_bcast:31
    return __builtin_bit_cast(float, __builtin_amdgcn_readlane(__builtin_bit_cast(int, x), 63));
}

// ---------------- CSR construction ----------------

__global__ void k_count(const int* __restrict__ dst, int* __restrict__ cnt) {
    int e = blockIdx.x * 256 + threadIdx.x;
    if (e < NE) atomicAdd(&cnt[dst[e]], 1);
}

__global__ __launch_bounds__(1024) void k_scan(const int* __restrict__ cnt, int* __restrict__ rowptr) {
    const int C = 40;  // 1024*40 >= 40000
    int t = threadIdx.x;
    int start = t * C;
    int end = min(start + C, NN);
    int local = 0;
    for (int i = start; i < end; ++i) local += cnt[i] + 1;  // +1 self loop
    __shared__ int ssum[1024];
    ssum[t] = local;
    __syncthreads();
    for (int off = 1; off < 1024; off <<= 1) {
        int v = (t >= off) ? ssum[t - off] : 0;
        __syncthreads();
        ssum[t] += v;
        __syncthreads();
    }
    int running = (t == 0) ? 0 : ssum[t - 1];
    for (int i = start; i < end; ++i) {
        rowptr[i] = running;
        running += cnt[i] + 1;
    }
    if (end == NN && start < NN) rowptr[NN] = running;
}

__global__ void k_csr_init(const int* __restrict__ rowptr, int* __restrict__ cursor) {
    int n = blockIdx.x * 256 + threadIdx.x;
    if (n < NN) cursor[n] = rowptr[n];
}

// fill CSR adjacency AND edge attrs in CSR order (linear s_load stream for k_gat)
__global__ void k_fill(const int* __restrict__ src, const int* __restrict__ dst,
                       const float* __restrict__ edge_attr,
                       int* __restrict__ cursor, int* __restrict__ csr_src, float* __restrict__ csr_ea) {
    int e = blockIdx.x * 256 + threadIdx.x;
    if (e < NE) {
        int d = dst[e];
        int p = atomicAdd(&cursor[d], 1);
        csr_src[p] = src[e];
        const float4* s4 = (const float4*)&edge_attr[(size_t)e * DEV];
        float4* d4 = (float4*)&csr_ea[(size_t)p * DEV];
        d4[0] = s4[0]; d4[1] = s4[1]; d4[2] = s4[2]; d4[3] = s4[3];
    }
}

// ---------------- weight permutation (all 3 layers, one launch) ----------------
// wp slot layout: [layer][128][128]; layer 0 uses first 64 rows.
__global__ void k_wperm_all(const float* __restrict__ w1l, const float* __restrict__ w1r,
                            const float* __restrict__ w2l, const float* __restrict__ w2r,
                            const float* __restrict__ w3l, const float* __restrict__ w3r,
                            float* __restrict__ wlp, float* __restrict__ wrp) {
    int i = blockIdx.x * 256 + threadIdx.x;
    if (i >= 3 * HDV * HDV) return;
    int layer = i / (HDV * HDV);
    int r = i - layer * HDV * HDV;
    int p = r & 127, kp = r >> 7;
    int K = (layer == 0) ? DINV : HDV;
    if (kp >= K) return;
    int kr = (layer == 0) ? kp : chan_of_pos(kp);   // rows positional for layers 2,3
    int cc = chan_of_pos(p);
    const float* wl = (layer == 0) ? w1l : (layer == 1) ? w2l : w3l;
    const float* wr = (layer == 0) ? w1r : (layer == 1) ? w2r : w3r;
    wlp[i] = wl[kr * HDV + cc];
    wrp[i] = wr[kr * HDV + cc];
}

// ---------------- dense transforms: XL = A@Wl, XR = A@Wr (prev-layer BN+leaky fused) ----------------
// 128x128 tile, 8x8 per-thread register blocking, double-buffered LDS, 1 sync/K-step.
__global__ __launch_bounds__(256) void k_gemm(const float* __restrict__ A, int K,
                                              const float* __restrict__ Wl, const float* __restrict__ Wr,
                                              float* __restrict__ XL, float* __restrict__ XR,
                                              const double* __restrict__ bnsum, const double* __restrict__ bnsumsq,
                                              const float* __restrict__ g, const float* __restrict__ bb) {
    __shared__ float As[2][8][128];
    __shared__ float Bs[2][8][128];
    __shared__ float ssc[HDV], ssh[HDV];
    int t = threadIdx.x;
    if (bnsum && t < HDV) {   // BN scale/shift of previous layer (positional index t)
        int c = chan_of_pos(t);
        double mu = bnsum[t] * (1.0 / NN);
        double var = bnsumsq[t] * (1.0 / NN) - mu * mu;
        double inv = rsqrt(var + 1e-5);
        float sc = (float)(inv * (double)g[c]);
        ssc[t] = sc;
        ssh[t] = bb[c] - (float)mu * sc;
    }
    __syncthreads();
    int rb = blockIdx.x * 128;
    const float* __restrict__ Bg = blockIdx.y ? Wr : Wl;
    float* __restrict__ Xout = blockIdx.y ? XR : XL;
    int tx = t & 15, ty = t >> 4;
    int lr_ = t >> 1, lk = (t & 1) * 4;     // A: thread loads float4 (row=lr_, k=lk..lk+3)
    int bk = t >> 5, bc = (t & 31) * 4;     // B: thread loads float4 (k=bk, col=bc..bc+3)

    auto loadA = [&](int k0) -> float4 {
        float4 av = (rb + lr_ < NN) ? *(const float4*)&A[(size_t)(rb + lr_) * K + k0 + lk]
                                    : float4{0.f, 0.f, 0.f, 0.f};
        if (bnsum) {
            int c0 = k0 + lk;
            av.x = fmaf(av.x, ssc[c0 + 0], ssh[c0 + 0]); av.x = fmaxf(av.x, 0.01f * av.x);
            av.y = fmaf(av.y, ssc[c0 + 1], ssh[c0 + 1]); av.y = fmaxf(av.y, 0.01f * av.y);
            av.z = fmaf(av.z, ssc[c0 + 2], ssh[c0 + 2]); av.z = fmaxf(av.z, 0.01f * av.z);
            av.w = fmaf(av.w, ssc[c0 + 3], ssh[c0 + 3]); av.w = fmaxf(av.w, 0.01f * av.w);
        }
        return av;
    };

    // prologue: stage tile 0
    float4 av = loadA(0);
    float4 bv = *(const float4*)&Bg[(size_t)bk * HDV + bc];
    As[0][lk + 0][lr_] = av.x; As[0][lk + 1][lr_] = av.y; As[0][lk + 2][lr_] = av.z; As[0][lk + 3][lr_] = av.w;
    *(float4*)&Bs[0][bk][bc] = bv;
    __syncthreads();

    float acc[8][8] = {};
    int cur = 0;
    for (int k0 = 0; k0 < K; k0 += 8) {
        bool more = (k0 + 8) < K;
        if (more) {   // issue next tile's loads; latency hides under compute below
            av = loadA(k0 + 8);
            bv = *(const float4*)&Bg[(size_t)(k0 + 8 + bk) * HDV + bc];
        }
        #pragma unroll
        for (int kk = 0; kk < 8; ++kk) {
            float a8[8], b8[8];
            *(float4*)&a8[0] = *(const float4*)&As[cur][kk][ty * 8];
            *(float4*)&a8[4] = *(const float4*)&As[cur][kk][ty * 8 + 4];
            *(float4*)&b8[0] = *(const float4*)&Bs[cur][kk][tx * 8];
            *(float4*)&b8[4] = *(const float4*)&Bs[cur][kk][tx * 8 + 4];
            #pragma unroll
            for (int ii = 0; ii < 8; ++ii)
                #pragma unroll
                for (int jj = 0; jj < 8; ++jj)
                    acc[ii][jj] = fmaf(a8[ii], b8[jj], acc[ii][jj]);
        }
        if (more) {
            int nxt = cur ^ 1;
            As[nxt][lk + 0][lr_] = av.x; As[nxt][lk + 1][lr_] = av.y;
            As[nxt][lk + 2][lr_] = av.z; As[nxt][lk + 3][lr_] = av.w;
            *(float4*)&Bs[nxt][bk][bc] = bv;
            __syncthreads();
            cur = nxt;
        }
    }
    #pragma unroll
    for (int ii = 0; ii < 8; ++ii) {
        int row = rb + ty * 8 + ii;
        if (row < NN) {
            float4 v0 = {acc[ii][0], acc[ii][1], acc[ii][2], acc[ii][3]};
            float4 v1 = {acc[ii][4], acc[ii][5], acc[ii][6], acc[ii][7]};
            *(float4*)&Xout[(size_t)row * HDV + tx * 8] = v0;
            *(float4*)&Xout[(size_t)row * HDV + tx * 8 + 4] = v1;
        }
    }
}

// ---------------- GATv2 per-node softmax aggregation ----------------
// one wave per node; lane L owns positions 2L,2L+1 = channels (L, 64+L) packed as float2.
// 4 independent edge slots in flight; self-loop handled LAST via running ee-sum:
//   ee_self = mean_j(ea_j) @ we = mean_j(ea_j @ we) = eesum / deg   (exact, linear)
__global__ __launch_bounds__(256) void k_gat(const float* __restrict__ XL, const float* __restrict__ XR,
                                             const int* __restrict__ rowptr, const int* __restrict__ csr_src,
                                             const float* __restrict__ csr_ea,
                                             const float* __restrict__ we, const float* __restrict__ att,
                                             const float* __restrict__ cb, float* __restrict__ hpre) {
    int t = threadIdx.x;
    int L = t & 63;
    int d = __builtin_amdgcn_readfirstlane(blockIdx.x * 4 + (t >> 6));
    v2f rwe0[DEV / 2], rwe1[DEV / 2];   // k-pairs per head: 32 VGPRs
    #pragma unroll
    for (int j = 0; j < DEV / 2; ++j) {
        rwe0[j] = v2f{we[(2 * j) * HDV + L],      we[(2 * j + 1) * HDV + L]};
        rwe1[j] = v2f{we[(2 * j) * HDV + 64 + L], we[(2 * j + 1) * HDV + 64 + L]};
    }
    const float LOG2E = 1.4426950408889634f;
    float attv0 = att[L] * LOG2E, attv1 = att[64 + L] * LOG2E;
    v2f xr = *(const v2f*)&XR[(size_t)d * HDV + 2 * L];
    int istart = rowptr[d];
    int iend = rowptr[d + 1] - 1;           // real edges only; last slot = self-loop
    int deg = iend - istart;
    v2f D0 = {0.f, 0.f}, D1 = {0.f, 0.f}, D2 = {0.f, 0.f}, D3 = {0.f, 0.f};
    v2f A0 = {0.f, 0.f}, A1 = {0.f, 0.f}, A2 = {0.f, 0.f}, A3 = {0.f, 0.f};
    v2f eesum = {0.f, 0.f};

    auto body = [&](int i, v2f& Dk, v2f& Ak) {
        int sx = csr_src[i];                          // s_load, linear
        const v2f* eap = (const v2f*)(csr_ea + (size_t)i * DEV);  // uniform pairs, linear
        unsigned off = ((unsigned)sx << 9) + ((unsigned)L << 3);
        v2f xl = *(const v2f*)((const char*)XL + off);  // 32-bit voffset gather
        v2f e0 = {0.f, 0.f}, e1 = {0.f, 0.f};
        #pragma unroll
        for (int j = 0; j < DEV / 2; ++j) {
            v2f ea2 = eap[j];
            e0 = __builtin_elementwise_fma(ea2, rwe0[j], e0);   // v_pk_fma_f32
            e1 = __builtin_elementwise_fma(ea2, rwe1[j], e1);
        }
        v2f eev = {e0.x + e0.y, e1.x + e1.y};
        eesum += eev;
        v2f m = xl + xr + eev;
        v2f lr = __builtin_elementwise_max(m, m * 0.2f);   // leaky_relu(0.2)
        float c0 = wave_sum64(lr.x * attv0);
        float c1 = wave_sum64(lr.y * attv1);
        v2f e = {__builtin_amdgcn_exp2f(c0), __builtin_amdgcn_exp2f(c1)};
        Dk += e;
        Ak = __builtin_elementwise_fma(e, xl, Ak);
    };

    int i = istart;
    int rem = deg & 3;
    if (rem > 0) { body(i, D0, A0); ++i; }
    if (rem > 1) { body(i, D1, A1); ++i; }
    if (rem > 2) { body(i, D2, A2); ++i; }
    for (; i < iend; i += 4) {
        body(i,     D0, A0);
        body(i + 1, D1, A1);
        body(i + 2, D2, A2);
        body(i + 3, D3, A3);
    }
    {   // self-loop: xl = own row, ee = mean of edge ee's (0 if deg==0)
        v2f xls = *(const v2f*)&XL[(size_t)d * HDV + 2 * L];
        v2f eeself = eesum * (1.0f / (float)max(deg, 1));
        v2f m = xls + xr + eeself;
        v2f lr = __builtin_elementwise_max(m, m * 0.2f);
        float c0 = wave_sum64(lr.x * attv0);
        float c1 = wave_sum64(lr.y * attv1);
        v2f e = {__builtin_amdgcn_exp2f(c0), __builtin_amdgcn_exp2f(c1)};
        D0 += e;
        A0 = __builtin_elementwise_fma(e, xls, A0);
    }
    v2f D = (D0 + D1) + (D2 + D3);
    v2f A = (A0 + A1) + (A2 + A3);
    v2f h = A / (D + 1e-16f) + v2f{cb[L], cb[64 + L]};
    *(v2f*)&hpre[(size_t)d * HDV + 2 * L] = h;
}

// ---------------- BatchNorm stats (position-indexed, fp32 partials) ----------------

__global__ __launch_bounds__(256) void k_bn_stats(const float* __restrict__ hpre,
                                                  double* __restrict__ bnsum, double* __restrict__ bnsumsq) {
    int c2 = (threadIdx.x & 63) * 2;
    int rg = threadIdx.x >> 6;          // 0..3
    int r0 = blockIdx.x * 250;
    v2f s = {0.f, 0.f}, q = {0.f, 0.f};
    for (int r = r0 + rg; r < r0 + 250; r += 4) {
        v2f v = *(const v2f*)&hpre[(size_t)r * HDV + c2];
        s += v;
        q = __builtin_elementwise_fma(v, v, q);
    }
    __shared__ v2f ls[256], lq[256];
    ls[threadIdx.x] = s; lq[threadIdx.x] = q;
    __syncthreads();
    if (rg == 0) {
        int b = threadIdx.x;
        s = ls[b] + ls[b + 64] + ls[b + 128] + ls[b + 192];
        q = lq[b] + lq[b + 64] + lq[b + 128] + lq[b + 192];
        atomicAdd(&bnsum[c2],     (double)s.x);
        atomicAdd(&bnsum[c2 + 1], (double)s.y);
        atomicAdd(&bnsumsq[c2],     (double)q.x);
        atomicAdd(&bnsumsq[c2 + 1], (double)q.y);
    }
}

// ---------------- pooling + MLP ----------------

__global__ void k_gbounds(const int* __restrict__ batch, int* __restrict__ gstart) {
    int g = threadIdx.x;
    if (g > NG) return;
    int lo = 0, hi = NN;
    while (lo < hi) {
        int mid = (lo + hi) >> 1;
        if (batch[mid] < g) lo = mid + 1; else hi = mid;
    }
    gstart[g] = lo;
}

// grid (NG, PSPLIT): partial sums with layer-3 BN+leaky fused; atomic add into zeroed pooled_sum
__global__ __launch_bounds__(256) void k_pool2(const float* __restrict__ hpre, const int* __restrict__ gstart,
                                               const double* __restrict__ bnsum, const double* __restrict__ bnsumsq,
                                               const float* __restrict__ g, const float* __restrict__ bb,
                                               float* __restrict__ pooled_sum) {
    __shared__ float ssc[HDV], ssh[HDV];
    int t = threadIdx.x;
    if (t < HDV) {
        int cc = chan_of_pos(t);
        double mu = bnsum[t] * (1.0 / NN);
        double var = bnsumsq[t] * (1.0 / NN) - mu * mu;
        double inv = rsqrt(var + 1e-5);
        float sc = (float)(inv * (double)g[cc]);
        ssc[t] = sc;
        ssh[t] = bb[cc] - (float)mu * sc;
    }
    __syncthreads();
    int gr = blockIdx.x, slice = blockIdx.y;
    int s = gstart[gr], e = gstart[gr + 1];
    int c = t & 127, half = t >> 7;
    float sc = ssc[c], sh = ssh[c];
    float acc = 0.f;
    for (int r = s + slice * 2 + half; r < e; r += PSPLIT * 2) {
        float v = fmaf(hpre[(size_t)r * HDV + c], sc, sh);
        acc += fmaxf(v, 0.01f * v);
    }
    __shared__ float ls[256];
    ls[t] = acc;
    __syncthreads();
    if (half == 0) atomicAdd(&pooled_sum[gr * HDV + c], acc + ls[t + 128]);
}

__global__ __launch_bounds__(512) void k_mlp(const float* __restrict__ pooled_sum, const int* __restrict__ gstart,
                                             const float* __restrict__ fc1w, const float* __restrict__ fc1b,
                                             const float* __restrict__ fc2w, const float* __restrict__ fc2b,
                                             float* __restrict__ out) {
    __shared__ float pl[NG * HDV];   // 32 KB (positional)
    __shared__ float hh[NG * 64];    // 16 KB
    int t = threadIdx.x;
    for (int i = t; i < NG * HDV; i += 512) {
        int gr = i >> 7;
        float cnt = (float)max(gstart[gr + 1] - gstart[gr], 1);
        pl[i] = pooled_sum[i] / cnt;
    }
    __syncthreads();
    for (int i = t; i < NG * 64; i += 512) {
        int gr = i >> 6, c = i & 63;
        float s = fc1b[c];
        for (int p = 0; p < HDV; ++p)
            s += pl[gr * HDV + p] * fc1w[chan_of_pos(p) * 64 + c];
        hh[i] = s > 0.f ? s : 0.f;
    }
    __syncthreads();
    if (t < NG) {
        float s = fc2b[0];
        for (int k = 0; k < 64; ++k) s += hh[t * 64 + k] * fc2w[k];
        out[t] = s;
    }
}

// ---------------- launch ----------------

extern "C" void kernel_launch(void* const* d_in, const int* in_sizes, int n_in,
                              void* d_out, int out_size, void* d_ws, size_t ws_size,
                              hipStream_t stream) {
    const float* x = (const float*)d_in[0];
    const int* ei = (const int*)d_in[1];
    const int* src = ei;
    const int* dst = ei + NE;
    const float* ea = (const float*)d_in[2];
    const int* batch = (const int*)d_in[3];
    const float* fc1w = (const float*)d_in[25];
    const float* fc1b = (const float*)d_in[26];
    const float* fc2w = (const float*)d_in[27];
    const float* fc2b = (const float*)d_in[28];
    float* out = (float*)d_out;

    char* ws = (char*)d_ws;
    size_t off = 0;
    auto alloc = [&](size_t bytes) -> void* {
        void* p = ws + off;
        off = (off + bytes + 255) & ~(size_t)255;
        return p;
    };

    // zero region (memset every launch)
    int* cnt = (int*)alloc(NN * 4);
    double* bnsum = (double*)alloc(3 * HDV * 8);
    double* bnsumsq = (double*)alloc(3 * HDV * 8);
    float* pooled_sum = (float*)alloc(NG * HDV * 4);
    size_t zero_bytes = off;

    int* rowptr = (int*)alloc((NN + 1) * 4);
    int* cursor = (int*)alloc(NN * 4);
    int* gstart = (int*)alloc((NG + 1) * 4);
    float* wlp = (float*)alloc(3 * HDV * HDV * 4);
    float* wrp = (float*)alloc(3 * HDV * HDV * 4);
    int* csr_src = (int*)alloc(((size_t)EF + 16) * 4);
    float* csr_ea = (float*)alloc(((size_t)EF * DEV + 64) * 4);
    float* XLb = (float*)alloc((size_t)NN * HDV * 4);
    float* XRb = (float*)alloc((size_t)NN * HDV * 4);
    float* hpre = (float*)alloc((size_t)NN * HDV * 4);
    (void)ws_size; (void)in_sizes; (void)n_in; (void)out_size;

    hipMemsetAsync(d_ws, 0, zero_bytes, stream);

    k_count<<<(NE + 255) / 256, 256, 0, stream>>>(dst, cnt);
    k_scan<<<1, 1024, 0, stream>>>(cnt, rowptr);
    k_csr_init<<<(NN + 255) / 256, 256, 0, stream>>>(rowptr, cursor);
    k_fill<<<(NE + 255) / 256, 256, 0, stream>>>(src, dst, ea, cursor, csr_src, csr_ea);
    k_gbounds<<<1, 128, 0, stream>>>(batch, gstart);
    k_wperm_all<<<(3 * HDV * HDV + 255) / 256, 256, 0, stream>>>(
        (const float*)d_in[4], (const float*)d_in[5],
        (const float*)d_in[11], (const float*)d_in[12],
        (const float*)d_in[18], (const float*)d_in[19], wlp, wrp);

    const float* actp = x;
    int K = DINV;
    for (int L = 0; L < 3; ++L) {
        const float* we = (const float*)d_in[4 + 7 * L + 2];
        const float* a  = (const float*)d_in[4 + 7 * L + 3];
        const float* cb = (const float*)d_in[4 + 7 * L + 4];

        const double* bs  = (L == 0) ? nullptr : bnsum + (size_t)(L - 1) * HDV;
        const double* bsq = (L == 0) ? nullptr : bnsumsq + (size_t)(L - 1) * HDV;
        const float* gg   = (L == 0) ? nullptr : (const float*)d_in[4 + 7 * (L - 1) + 5];
        const float* bbp  = (L == 0) ? nullptr : (const float*)d_in[4 + 7 * (L - 1) + 6];

        k_gemm<<<dim3((NN + 127) / 128, 2), 256, 0, stream>>>(
            actp, K, wlp + (size_t)L * HDV * HDV, wrp + (size_t)L * HDV * HDV,
            XLb, XRb, bs, bsq, gg, bbp);
        k_gat<<<NN / 4, 256, 0, stream>>>(XLb, XRb, rowptr, csr_src, csr_ea, we, a, cb, hpre);
        k_bn_stats<<<160, 256, 0, stream>>>(hpre, bnsum + (size_t)L * HDV, bnsumsq + (size_t)L * HDV);
        actp = hpre;
        K = HDV;
    }

    k_pool2<<<dim3(NG, PSPLIT), 256, 0, stream>>>(
        hpre, gstart, bnsum + 2 * HDV, bnsumsq + 2 * HDV,
        (const float*)d_in[4 + 7 * 2 + 5], (const float*)d_in[4 + 7 * 2 + 6], pooled_sum);
    k_mlp<<<1, 512, 0, stream>>>(pooled_sum, gstart, fc1w, fc1b, fc2w, fc2b, out);
}

// Round 10
// 602.280 us; speedup vs baseline: 1.0228x; 1.0228x over previous
//
#include <hip/hip_runtime.h>
#include <hip/hip_fp16.h>
#include <math.h>

#define NN 40000
#define NE 640000
#define NG 64
#define DINV 64
#define HDV 128
#define DEV 16
#define EF (NE + NN)
#define PSPLIT 16

typedef float v2f __attribute__((ext_vector_type(2)));

// channel c <-> position pos(c)=2*(c&63)+(c>>6); position p <-> channel chan(p)=(p>>1)+64*(p&1)
__device__ __forceinline__ int chan_of_pos(int p) { return (p >> 1) + 64 * (p & 1); }

// ---------------- DPP wave-64 sum (rocPRIM sequence), result uniform ----------------
template <int CTRL>
__device__ __forceinline__ float dpp_mov_f(float x) {
    return __builtin_bit_cast(float,
        __builtin_amdgcn_update_dpp(0, __builtin_bit_cast(int, x), CTRL, 0xf, 0xf, true));
}
__device__ __forceinline__ float wave_sum64(float x) {
    x += dpp_mov_f<0x111>(x);   // row_shr:1
    x += dpp_mov_f<0x112>(x);   // row_shr:2
    x += dpp_mov_f<0x114>(x);   // row_shr:4
    x += dpp_mov_f<0x118>(x);   // row_shr:8
    x += dpp_mov_f<0x142>(x);   // row_bcast:15
    x += dpp_mov_f<0x143>(x);   // row_bcast:31
    return __builtin_bit_cast(float, __builtin_amdgcn_readlane(__builtin_bit_cast(int, x), 63));
}

// ---------------- CSR construction ----------------

__global__ void k_count(const int* __restrict__ dst, int* __restrict__ cnt) {
    int e = blockIdx.x * 256 + threadIdx.x;
    if (e < NE) atomicAdd(&cnt[dst[e]], 1);
}

__global__ __launch_bounds__(1024) void k_scan(const int* __restrict__ cnt, int* __restrict__ rowptr,
                                               int* __restrict__ cursor) {
    const int C = 40;  // 1024*40 >= 40000
    int t = threadIdx.x;
    int start = t * C;
    int end = min(start + C, NN);
    int local = 0;
    for (int i = start; i < end; ++i) local += cnt[i] + 1;  // +1 self loop
    __shared__ int ssum[1024];
    ssum[t] = local;
    __syncthreads();
    for (int off = 1; off < 1024; off <<= 1) {
        int v = (t >= off) ? ssum[t - off] : 0;
        __syncthreads();
        ssum[t] += v;
        __syncthreads();
    }
    int running = (t == 0) ? 0 : ssum[t - 1];
    for (int i = start; i < end; ++i) {
        rowptr[i] = running;
        cursor[i] = running;
        running += cnt[i] + 1;
    }
    if (end == NN && start < NN) rowptr[NN] = running;
}

// fill CSR adjacency AND edge attrs in CSR order (linear s_load stream for k_gat)
__global__ void k_fill(const int* __restrict__ src, const int* __restrict__ dst,
                       const float* __restrict__ edge_attr,
                       int* __restrict__ cursor, int* __restrict__ csr_src, float* __restrict__ csr_ea) {
    int e = blockIdx.x * 256 + threadIdx.x;
    if (e < NE) {
        int d = dst[e];
        int p = atomicAdd(&cursor[d], 1);
        csr_src[p] = src[e];
        const float4* s4 = (const float4*)&edge_attr[(size_t)e * DEV];
        float4* d4 = (float4*)&csr_ea[(size_t)p * DEV];
        d4[0] = s4[0]; d4[1] = s4[1]; d4[2] = s4[2]; d4[3] = s4[3];
    }
}

// ---------------- weight permutation (all 3 layers) + graph bounds, one launch ----------------
// wp slot layout: [layer][128][128]; layer 0 uses first 64 rows. Last block does gbounds.
__global__ void k_wperm_all(const float* __restrict__ w1l, const float* __restrict__ w1r,
                            const float* __restrict__ w2l, const float* __restrict__ w2r,
                            const float* __restrict__ w3l, const float* __restrict__ w3r,
                            float* __restrict__ wlp, float* __restrict__ wrp,
                            const int* __restrict__ batch, int* __restrict__ gstart) {
    int t = threadIdx.x;
    if (blockIdx.x == gridDim.x - 1) {   // graph boundaries via binary search (batch sorted)
        int g = t;
        if (g > NG) return;
        int lo = 0, hi = NN;
        while (lo < hi) {
            int mid = (lo + hi) >> 1;
            if (batch[mid] < g) lo = mid + 1; else hi = mid;
        }
        gstart[g] = lo;
        return;
    }
    int i = blockIdx.x * 256 + t;
    if (i >= 3 * HDV * HDV) return;
    int layer = i / (HDV * HDV);
    int r = i - layer * HDV * HDV;
    int p = r & 127, kp = r >> 7;
    int K = (layer == 0) ? DINV : HDV;
    if (kp >= K) return;
    int kr = (layer == 0) ? kp : chan_of_pos(kp);   // rows positional for layers 2,3
    int cc = chan_of_pos(p);
    const float* wl = (layer == 0) ? w1l : (layer == 1) ? w2l : w3l;
    const float* wr = (layer == 0) ? w1r : (layer == 1) ? w2r : w3r;
    wlp[i] = wl[kr * HDV + cc];
    wrp[i] = wr[kr * HDV + cc];
}

// ---------------- dense transforms: XL = A@Wl (fp16 out), XR = A@Wr (fp32 out) ----------------
// 128x128 tile, 8x8 per-thread register blocking, double-buffered LDS, 1 sync/K-step.
__global__ __launch_bounds__(256) void k_gemm(const float* __restrict__ A, int K,
                                              const float* __restrict__ Wl, const float* __restrict__ Wr,
                                              __half* __restrict__ XLh, float* __restrict__ XR,
                                              const double* __restrict__ bnsum, const double* __restrict__ bnsumsq,
                                              const float* __restrict__ g, const float* __restrict__ bb) {
    __shared__ float As[2][8][128];
    __shared__ float Bs[2][8][128];
    __shared__ float ssc[HDV], ssh[HDV];
    int t = threadIdx.x;
    if (bnsum && t < HDV) {   // BN scale/shift of previous layer (positional index t)
        int c = chan_of_pos(t);
        double mu = bnsum[t] * (1.0 / NN);
        double var = bnsumsq[t] * (1.0 / NN) - mu * mu;
        double inv = rsqrt(var + 1e-5);
        float sc = (float)(inv * (double)g[c]);
        ssc[t] = sc;
        ssh[t] = bb[c] - (float)mu * sc;
    }
    __syncthreads();
    int rb = blockIdx.x * 128;
    const float* __restrict__ Bg = blockIdx.y ? Wr : Wl;
    int tx = t & 15, ty = t >> 4;
    int lr_ = t >> 1, lk = (t & 1) * 4;     // A: thread loads float4 (row=lr_, k=lk..lk+3)
    int bk = t >> 5, bc = (t & 31) * 4;     // B: thread loads float4 (k=bk, col=bc..bc+3)

    auto loadA = [&](int k0) -> float4 {
        float4 av = (rb + lr_ < NN) ? *(const float4*)&A[(size_t)(rb + lr_) * K + k0 + lk]
                                    : float4{0.f, 0.f, 0.f, 0.f};
        if (bnsum) {
            int c0 = k0 + lk;
            av.x = fmaf(av.x, ssc[c0 + 0], ssh[c0 + 0]); av.x = fmaxf(av.x, 0.01f * av.x);
            av.y = fmaf(av.y, ssc[c0 + 1], ssh[c0 + 1]); av.y = fmaxf(av.y, 0.01f * av.y);
            av.z = fmaf(av.z, ssc[c0 + 2], ssh[c0 + 2]); av.z = fmaxf(av.z, 0.01f * av.z);
            av.w = fmaf(av.w, ssc[c0 + 3], ssh[c0 + 3]); av.w = fmaxf(av.w, 0.01f * av.w);
        }
        return av;
    };

    // prologue: stage tile 0
    float4 av = loadA(0);
    float4 bv = *(const float4*)&Bg[(size_t)bk * HDV + bc];
    As[0][lk + 0][lr_] = av.x; As[0][lk + 1][lr_] = av.y; As[0][lk + 2][lr_] = av.z; As[0][lk + 3][lr_] = av.w;
    *(float4*)&Bs[0][bk][bc] = bv;
    __syncthreads();

    float acc[8][8] = {};
    int cur = 0;
    for (int k0 = 0; k0 < K; k0 += 8) {
        bool more = (k0 + 8) < K;
        if (more) {   // issue next tile's loads; latency hides under compute below
            av = loadA(k0 + 8);
            bv = *(const float4*)&Bg[(size_t)(k0 + 8 + bk) * HDV + bc];
        }
        #pragma unroll
        for (int kk = 0; kk < 8; ++kk) {
            float a8[8], b8[8];
            *(float4*)&a8[0] = *(const float4*)&As[cur][kk][ty * 8];
            *(float4*)&a8[4] = *(const float4*)&As[cur][kk][ty * 8 + 4];
            *(float4*)&b8[0] = *(const float4*)&Bs[cur][kk][tx * 8];
            *(float4*)&b8[4] = *(const float4*)&Bs[cur][kk][tx * 8 + 4];
            #pragma unroll
            for (int ii = 0; ii < 8; ++ii)
                #pragma unroll
                for (int jj = 0; jj < 8; ++jj)
                    acc[ii][jj] = fmaf(a8[ii], b8[jj], acc[ii][jj]);
        }
        if (more) {
            int nxt = cur ^ 1;
            As[nxt][lk + 0][lr_] = av.x; As[nxt][lk + 1][lr_] = av.y;
            As[nxt][lk + 2][lr_] = av.z; As[nxt][lk + 3][lr_] = av.w;
            *(float4*)&Bs[nxt][bk][bc] = bv;
            __syncthreads();
            cur = nxt;
        }
    }
    if (blockIdx.y == 0) {   // XL: fp16 output
        #pragma unroll
        for (int ii = 0; ii < 8; ++ii) {
            int row = rb + ty * 8 + ii;
            if (row < NN) {
                __half2 h4[4];
                #pragma unroll
                for (int jj = 0; jj < 4; ++jj)
                    h4[jj] = __half2{__float2half_rn(acc[ii][2 * jj]), __float2half_rn(acc[ii][2 * jj + 1])};
                *(__half2*)&XLh[(size_t)row * HDV + tx * 8 + 0] = h4[0];
                *(__half2*)&XLh[(size_t)row * HDV + tx * 8 + 2] = h4[1];
                *(__half2*)&XLh[(size_t)row * HDV + tx * 8 + 4] = h4[2];
                *(__half2*)&XLh[(size_t)row * HDV + tx * 8 + 6] = h4[3];
            }
        }
    } else {                 // XR: fp32 output
        #pragma unroll
        for (int ii = 0; ii < 8; ++ii) {
            int row = rb + ty * 8 + ii;
            if (row < NN) {
                float4 v0 = {acc[ii][0], acc[ii][1], acc[ii][2], acc[ii][3]};
                float4 v1 = {acc[ii][4], acc[ii][5], acc[ii][6], acc[ii][7]};
                *(float4*)&XR[(size_t)row * HDV + tx * 8] = v0;
                *(float4*)&XR[(size_t)row * HDV + tx * 8 + 4] = v1;
            }
        }
    }
}

// ---------------- GATv2 per-node softmax aggregation ----------------
// one wave per node; lane L owns positions 2L,2L+1 = channels (L, 64+L) packed as float2.
// XL is fp16 (halved gather traffic); self-loop handled LAST via running ee-sum:
//   ee_self = mean_j(ea_j) @ we = mean_j(ea_j @ we) = eesum / deg   (exact, linear)
__global__ __launch_bounds__(256) void k_gat(const __half* __restrict__ XLh, const float* __restrict__ XR,
                                             const int* __restrict__ rowptr, const int* __restrict__ csr_src,
                                             const float* __restrict__ csr_ea,
                                             const float* __restrict__ we, const float* __restrict__ att,
                                             const float* __restrict__ cb, float* __restrict__ hpre) {
    int t = threadIdx.x;
    int L = t & 63;
    int d = __builtin_amdgcn_readfirstlane(blockIdx.x * 4 + (t >> 6));
    v2f rwe0[DEV / 2], rwe1[DEV / 2];   // k-pairs per head: 32 VGPRs
    #pragma unroll
    for (int j = 0; j < DEV / 2; ++j) {
        rwe0[j] = v2f{we[(2 * j) * HDV + L],      we[(2 * j + 1) * HDV + L]};
        rwe1[j] = v2f{we[(2 * j) * HDV + 64 + L], we[(2 * j + 1) * HDV + 64 + L]};
    }
    const float LOG2E = 1.4426950408889634f;
    float attv0 = att[L] * LOG2E, attv1 = att[64 + L] * LOG2E;
    v2f xr = *(const v2f*)&XR[(size_t)d * HDV + 2 * L];
    int istart = rowptr[d];
    int iend = rowptr[d + 1] - 1;           // real edges only; last slot = self-loop
    int deg = iend - istart;
    v2f Da = {0.f, 0.f}, Db = {0.f, 0.f}, Aa = {0.f, 0.f}, Ab = {0.f, 0.f};
    v2f eesum = {0.f, 0.f};

    auto body = [&](int i, v2f& Dk, v2f& Ak) {
        int sx = csr_src[i];                          // s_load, linear
        const v2f* eap = (const v2f*)(csr_ea + (size_t)i * DEV);  // uniform pairs, linear
        unsigned off = ((unsigned)sx << 8) + ((unsigned)L << 2);  // fp16 row = 256 B
        __half2 xlh = *(const __half2*)((const char*)XLh + off);  // one dword gather
        v2f xl = {__half2float(xlh.x), __half2float(xlh.y)};
        v2f e0 = {0.f, 0.f}, e1 = {0.f, 0.f};
        #pragma unroll
        for (int j = 0; j < DEV / 2; ++j) {
            v2f ea2 = eap[j];
            e0 = __builtin_elementwise_fma(ea2, rwe0[j], e0);   // v_pk_fma_f32
            e1 = __builtin_elementwise_fma(ea2, rwe1[j], e1);
        }
        v2f eev = {e0.x + e0.y, e1.x + e1.y};
        eesum += eev;
        v2f m = xl + xr + eev;
        v2f lr = __builtin_elementwise_max(m, m * 0.2f);   // leaky_relu(0.2)
        float c0 = wave_sum64(lr.x * attv0);
        float c1 = wave_sum64(lr.y * attv1);
        v2f e = {__builtin_amdgcn_exp2f(c0), __builtin_amdgcn_exp2f(c1)};
        Dk += e;
        Ak = __builtin_elementwise_fma(e, xl, Ak);
    };

    int i = istart;
    if (deg & 1) { body(i, Da, Aa); ++i; }
    for (; i < iend; i += 2) {
        body(i,     Da, Aa);
        body(i + 1, Db, Ab);
    }
    {   // self-loop: xl = own row, ee = mean of edge ee's (0 if deg==0)
        __half2 xlh = *(const __half2*)&XLh[(size_t)d * HDV + 2 * L];
        v2f xls = {__half2float(xlh.x), __half2float(xlh.y)};
        v2f eeself = eesum * (1.0f / (float)max(deg, 1));
        v2f m = xls + xr + eeself;
        v2f lr = __builtin_elementwise_max(m, m * 0.2f);
        float c0 = wave_sum64(lr.x * attv0);
        float c1 = wave_sum64(lr.y * attv1);
        v2f e = {__builtin_amdgcn_exp2f(c0), __builtin_amdgcn_exp2f(c1)};
        Da += e;
        Aa = __builtin_elementwise_fma(e, xls, Aa);
    }
    v2f D = Da + Db;
    v2f A = Aa + Ab;
    v2f h = A / (D + 1e-16f) + v2f{cb[L], cb[64 + L]};
    *(v2f*)&hpre[(size_t)d * HDV + 2 * L] = h;
}

// ---------------- BatchNorm stats (position-indexed, fp32 partials) ----------------

__global__ __launch_bounds__(256) void k_bn_stats(const float* __restrict__ hpre,
                                                  double* __restrict__ bnsum, double* __restrict__ bnsumsq) {
    int c2 = (threadIdx.x & 63) * 2;
    int rg = threadIdx.x >> 6;          // 0..3
    int r0 = blockIdx.x * 250;
    v2f s = {0.f, 0.f}, q = {0.f, 0.f};
    for (int r = r0 + rg; r < r0 + 250; r += 4) {
        v2f v = *(const v2f*)&hpre[(size_t)r * HDV + c2];
        s += v;
        q = __builtin_elementwise_fma(v, v, q);
    }
    __shared__ v2f ls[256], lq[256];
    ls[threadIdx.x] = s; lq[threadIdx.x] = q;
    __syncthreads();
    if (rg == 0) {
        int b = threadIdx.x;
        s = ls[b] + ls[b + 64] + ls[b + 128] + ls[b + 192];
        q = lq[b] + lq[b + 64] + lq[b + 128] + lq[b + 192];
        atomicAdd(&bnsum[c2],     (double)s.x);
        atomicAdd(&bnsum[c2 + 1], (double)s.y);
        atomicAdd(&bnsumsq[c2],     (double)q.x);
        atomicAdd(&bnsumsq[c2 + 1], (double)q.y);
    }
}

// ---------------- pooling + MLP ----------------

// grid (NG, PSPLIT): partial sums with layer-3 BN+leaky fused; atomic add into zeroed pooled_sum
__global__ __launch_bounds__(256) void k_pool2(const float* __restrict__ hpre, const int* __restrict__ gstart,
                                               const double* __restrict__ bnsum, const double* __restrict__ bnsumsq,
                                               const float* __restrict__ g, const float* __restrict__ bb,
                                               float* __restrict__ pooled_sum) {
    __shared__ float ssc[HDV], ssh[HDV];
    int t = threadIdx.x;
    if (t < HDV) {
        int cc = chan_of_pos(t);
        double mu = bnsum[t] * (1.0 / NN);
        double var = bnsumsq[t] * (1.0 / NN) - mu * mu;
        double inv = rsqrt(var + 1e-5);
        float sc = (float)(inv * (double)g[cc]);
        ssc[t] = sc;
        ssh[t] = bb[cc] - (float)mu * sc;
    }
    __syncthreads();
    int gr = blockIdx.x, slice = blockIdx.y;
    int s = gstart[gr], e = gstart[gr + 1];
    int c = t & 127, half = t >> 7;
    float sc = ssc[c], sh = ssh[c];
    float acc = 0.f;
    for (int r = s + slice * 2 + half; r < e; r += PSPLIT * 2) {
        float v = fmaf(hpre[(size_t)r * HDV + c], sc, sh);
        acc += fmaxf(v, 0.01f * v);
    }
    __shared__ float ls[256];
    ls[t] = acc;
    __syncthreads();
    if (half == 0) atomicAdd(&pooled_sum[gr * HDV + c], acc + ls[t + 128]);
}

__global__ __launch_bounds__(512) void k_mlp(const float* __restrict__ pooled_sum, const int* __restrict__ gstart,
                                             const float* __restrict__ fc1w, const float* __restrict__ fc1b,
                                             const float* __restrict__ fc2w, const float* __restrict__ fc2b,
                                             float* __restrict__ out) {
    __shared__ float pl[NG * HDV];   // 32 KB (positional)
    __shared__ float hh[NG * 64];    // 16 KB
    int t = threadIdx.x;
    for (int i = t; i < NG * HDV; i += 512) {
        int gr = i >> 7;
        float cnt = (float)max(gstart[gr + 1] - gstart[gr], 1);
        pl[i] = pooled_sum[i] / cnt;
    }
    __syncthreads();
    for (int i = t; i < NG * 64; i += 512) {
        int gr = i >> 6, c = i & 63;
        float s = fc1b[c];
        for (int p = 0; p < HDV; ++p)
            s += pl[gr * HDV + p] * fc1w[chan_of_pos(p) * 64 + c];
        hh[i] = s > 0.f ? s : 0.f;
    }
    __syncthreads();
    if (t < NG) {
        float s = fc2b[0];
        for (int k = 0; k < 64; ++k) s += hh[t * 64 + k] * fc2w[k];
        out[t] = s;
    }
}

// ---------------- launch ----------------

extern "C" void kernel_launch(void* const* d_in, const int* in_sizes, int n_in,
                              void* d_out, int out_size, void* d_ws, size_t ws_size,
                              hipStream_t stream) {
    const float* x = (const float*)d_in[0];
    const int* ei = (const int*)d_in[1];
    const int* src = ei;
    const int* dst = ei + NE;
    const float* ea = (const float*)d_in[2];
    const int* batch = (const int*)d_in[3];
    const float* fc1w = (const float*)d_in[25];
    const float* fc1b = (const float*)d_in[26];
    const float* fc2w = (const float*)d_in[27];
    const float* fc2b = (const float*)d_in[28];
    float* out = (float*)d_out;

    char* ws = (char*)d_ws;
    size_t off = 0;
    auto alloc = [&](size_t bytes) -> void* {
        void* p = ws + off;
        off = (off + bytes + 255) & ~(size_t)255;
        return p;
    };

    // zero region (memset every launch)
    int* cnt = (int*)alloc(NN * 4);
    double* bnsum = (double*)alloc(3 * HDV * 8);
    double* bnsumsq = (double*)alloc(3 * HDV * 8);
    float* pooled_sum = (float*)alloc(NG * HDV * 4);
    size_t zero_bytes = off;

    int* rowptr = (int*)alloc((NN + 1) * 4);
    int* cursor = (int*)alloc(NN * 4);
    int* gstart = (int*)alloc((NG + 1) * 4);
    float* wlp = (float*)alloc(3 * HDV * HDV * 4);
    float* wrp = (float*)alloc(3 * HDV * HDV * 4);
    int* csr_src = (int*)alloc(((size_t)EF + 16) * 4);
    float* csr_ea = (float*)alloc(((size_t)EF * DEV + 64) * 4);
    __half* XLh = (__half*)alloc((size_t)NN * HDV * 2);
    float* XRb = (float*)alloc((size_t)NN * HDV * 4);
    float* hpre = (float*)alloc((size_t)NN * HDV * 4);
    (void)ws_size; (void)in_sizes; (void)n_in; (void)out_size;

    hipMemsetAsync(d_ws, 0, zero_bytes, stream);

    k_count<<<(NE + 255) / 256, 256, 0, stream>>>(dst, cnt);
    k_scan<<<1, 1024, 0, stream>>>(cnt, rowptr, cursor);
    k_fill<<<(NE + 255) / 256, 256, 0, stream>>>(src, dst, ea, cursor, csr_src, csr_ea);
    k_wperm_all<<<(3 * HDV * HDV + 255) / 256 + 1, 256, 0, stream>>>(
        (const float*)d_in[4], (const float*)d_in[5],
        (const float*)d_in[11], (const float*)d_in[12],
        (const float*)d_in[18], (const float*)d_in[19], wlp, wrp, batch, gstart);

    const float* actp = x;
    int K = DINV;
    for (int L = 0; L < 3; ++L) {
        const float* we = (const float*)d_in[4 + 7 * L + 2];
        const float* a  = (const float*)d_in[4 + 7 * L + 3];
        const float* cb = (const float*)d_in[4 + 7 * L + 4];

        const double* bs  = (L == 0) ? nullptr : bnsum + (size_t)(L - 1) * HDV;
        const double* bsq = (L == 0) ? nullptr : bnsumsq + (size_t)(L - 1) * HDV;
        const float* gg   = (L == 0) ? nullptr : (const float*)d_in[4 + 7 * (L - 1) + 5];
        const float* bbp  = (L == 0) ? nullptr : (const float*)d_in[4 + 7 * (L - 1) + 6];

        k_gemm<<<dim3((NN + 127) / 128, 2), 256, 0, stream>>>(
            actp, K, wlp + (size_t)L * HDV * HDV, wrp + (size_t)L * HDV * HDV,
            XLh, XRb, bs, bsq, gg, bbp);
        k_gat<<<NN / 4, 256, 0, stream>>>(XLh, XRb, rowptr, csr_src, csr_ea, we, a, cb, hpre);
        k_bn_stats<<<160, 256, 0, stream>>>(hpre, bnsum + (size_t)L * HDV, bnsumsq + (size_t)L * HDV);
        actp = hpre;
        K = HDV;
    }

    k_pool2<<<dim3(NG, PSPLIT), 256, 0, stream>>>(
        hpre, gstart, bnsum + 2 * HDV, bnsumsq + 2 * HDV,
        (const float*)d_in[4 + 7 * 2 + 5], (const float*)d_in[4 + 7 * 2 + 6], pooled_sum);
    k_mlp<<<1, 512, 0, stream>>>(pooled_sum, gstart, fc1w, fc1b, fc2w, fc2b, out);
}

// Round 11
// 520.838 us; speedup vs baseline: 1.1827x; 1.1564x over previous
//
#include <hip/hip_runtime.h>
#include <hip/hip_fp16.h>
#include <math.h>

#define NN 40000
#define NE 640000
#define NG 64
#define DINV 64
#define HDV 128
#define DEV 16
#define EF (NE + NN)
#define PSPLIT 16
#define NSB ((NN + 255) / 256)   // 157 scan blocks

typedef float v2f __attribute__((ext_vector_type(2)));

// channel c <-> position pos(c)=2*(c&63)+(c>>6); position p <-> channel chan(p)=(p>>1)+64*(p&1)
__device__ __forceinline__ int chan_of_pos(int p) { return (p >> 1) + 64 * (p & 1); }

// ---------------- DPP wave-64 sum (rocPRIM sequence), result uniform ----------------
template <int CTRL>
__device__ __forceinline__ float dpp_mov_f(float x) {
    return __builtin_bit_cast(float,
        __builtin_amdgcn_update_dpp(0, __builtin_bit_cast(int, x), CTRL, 0xf, 0xf, true));
}
__device__ __forceinline__ float wave_sum64(float x) {
    x += dpp_mov_f<0x111>(x);   // row_shr:1
    x += dpp_mov_f<0x112>(x);   // row_shr:2
    x += dpp_mov_f<0x114>(x);   // row_shr:4
    x += dpp_mov_f<0x118>(x);   // row_shr:8
    x += dpp_mov_f<0x142>(x);   // row_bcast:15
    x += dpp_mov_f<0x143>(x);   // row_bcast:31
    return __builtin_bit_cast(float, __builtin_amdgcn_readlane(__builtin_bit_cast(int, x), 63));
}

// ---------------- CSR construction ----------------

__global__ void k_count(const int* __restrict__ dst, int* __restrict__ cnt) {
    int e = blockIdx.x * 256 + threadIdx.x;
    if (e < NE) atomicAdd(&cnt[dst[e]], 1);
}

// hierarchical coalesced scan of (cnt[i]+1): a) block sums, b) scan sums, c) final
__global__ __launch_bounds__(256) void k_scan_a(const int* __restrict__ cnt, int* __restrict__ bsum) {
    int i = blockIdx.x * 256 + threadIdx.x;
    int v = (i < NN) ? cnt[i] + 1 : 0;
    __shared__ int s[256];
    s[threadIdx.x] = v;
    __syncthreads();
    for (int off = 128; off > 0; off >>= 1) {
        if (threadIdx.x < off) s[threadIdx.x] += s[threadIdx.x + off];
        __syncthreads();
    }
    if (threadIdx.x == 0) bsum[blockIdx.x] = s[0];
}

__global__ __launch_bounds__(256) void k_scan_b(const int* __restrict__ bsum, int* __restrict__ boff) {
    int t = threadIdx.x;
    int v = (t < NSB) ? bsum[t] : 0;
    __shared__ int s[256];
    s[t] = v;
    __syncthreads();
    for (int off = 1; off < 256; off <<= 1) {
        int add = (t >= off) ? s[t - off] : 0;
        __syncthreads();
        s[t] += add;
        __syncthreads();
    }
    boff[t] = s[t] - v;   // exclusive
}

__global__ __launch_bounds__(256) void k_scan_c(const int* __restrict__ cnt, const int* __restrict__ boff,
                                                int* __restrict__ rowptr, int* __restrict__ cursor) {
    int i = blockIdx.x * 256 + threadIdx.x;
    int t = threadIdx.x;
    int v = (i < NN) ? cnt[i] + 1 : 0;
    __shared__ int s[256];
    s[t] = v;
    __syncthreads();
    for (int off = 1; off < 256; off <<= 1) {
        int add = (t >= off) ? s[t - off] : 0;
        __syncthreads();
        s[t] += add;
        __syncthreads();
    }
    int excl = boff[blockIdx.x] + s[t] - v;
    if (i < NN) {
        rowptr[i] = excl;
        cursor[i] = excl;
        if (i == NN - 1) rowptr[NN] = excl + v;   // = EF
    }
}

// fill CSR adjacency AND edge attrs in CSR order (linear s_load stream for k_gat)
__global__ void k_fill(const int* __restrict__ src, const int* __restrict__ dst,
                       const float* __restrict__ edge_attr,
                       int* __restrict__ cursor, int* __restrict__ csr_src, float* __restrict__ csr_ea) {
    int e = blockIdx.x * 256 + threadIdx.x;
    if (e < NE) {
        int d = dst[e];
        int p = atomicAdd(&cursor[d], 1);
        csr_src[p] = src[e];
        const float4* s4 = (const float4*)&edge_attr[(size_t)e * DEV];
        float4* d4 = (float4*)&csr_ea[(size_t)p * DEV];
        d4[0] = s4[0]; d4[1] = s4[1]; d4[2] = s4[2]; d4[3] = s4[3];
    }
}

// ---------------- weight permutation (all 3 layers) + graph bounds, one launch ----------------
// wp slot layout: [layer][128][128]; layer 0 uses first 64 rows. Last block does gbounds.
__global__ void k_wperm_all(const float* __restrict__ w1l, const float* __restrict__ w1r,
                            const float* __restrict__ w2l, const float* __restrict__ w2r,
                            const float* __restrict__ w3l, const float* __restrict__ w3r,
                            float* __restrict__ wlp, float* __restrict__ wrp,
                            const int* __restrict__ batch, int* __restrict__ gstart) {
    int t = threadIdx.x;
    if (blockIdx.x == gridDim.x - 1) {   // graph boundaries via binary search (batch sorted)
        int g = t;
        if (g > NG) return;
        int lo = 0, hi = NN;
        while (lo < hi) {
            int mid = (lo + hi) >> 1;
            if (batch[mid] < g) lo = mid + 1; else hi = mid;
        }
        gstart[g] = lo;
        return;
    }
    int i = blockIdx.x * 256 + t;
    if (i >= 3 * HDV * HDV) return;
    int layer = i / (HDV * HDV);
    int r = i - layer * HDV * HDV;
    int p = r & 127, kp = r >> 7;
    int K = (layer == 0) ? DINV : HDV;
    if (kp >= K) return;
    int kr = (layer == 0) ? kp : chan_of_pos(kp);   // rows positional for layers 2,3
    int cc = chan_of_pos(p);
    const float* wl = (layer == 0) ? w1l : (layer == 1) ? w2l : w3l;
    const float* wr = (layer == 0) ? w1r : (layer == 1) ? w2r : w3r;
    wlp[i] = wl[kr * HDV + cc];
    wrp[i] = wr[kr * HDV + cc];
}

// ---------------- dense transforms: XL = A@Wl (fp16 out), XR = A@Wr (fp32 out) ----------------
// 128x128 tile, 8x8 per-thread register blocking, double-buffered LDS, 1 sync/K-step.
__global__ __launch_bounds__(256) void k_gemm(const float* __restrict__ A, int K,
                                              const float* __restrict__ Wl, const float* __restrict__ Wr,
                                              __half* __restrict__ XLh, float* __restrict__ XR,
                                              const double* __restrict__ bnsum, const double* __restrict__ bnsumsq,
                                              const float* __restrict__ g, const float* __restrict__ bb) {
    __shared__ float As[2][8][128];
    __shared__ float Bs[2][8][128];
    __shared__ float ssc[HDV], ssh[HDV];
    int t = threadIdx.x;
    if (bnsum && t < HDV) {   // BN scale/shift of previous layer (positional index t)
        int c = chan_of_pos(t);
        double mu = bnsum[t] * (1.0 / NN);
        double var = bnsumsq[t] * (1.0 / NN) - mu * mu;
        double inv = rsqrt(var + 1e-5);
        float sc = (float)(inv * (double)g[c]);
        ssc[t] = sc;
        ssh[t] = bb[c] - (float)mu * sc;
    }
    __syncthreads();
    int rb = blockIdx.x * 128;
    const float* __restrict__ Bg = blockIdx.y ? Wr : Wl;
    int tx = t & 15, ty = t >> 4;
    int lr_ = t >> 1, lk = (t & 1) * 4;     // A: thread loads float4 (row=lr_, k=lk..lk+3)
    int bk = t >> 5, bc = (t & 31) * 4;     // B: thread loads float4 (k=bk, col=bc..bc+3)

    auto loadA = [&](int k0) -> float4 {
        float4 av = (rb + lr_ < NN) ? *(const float4*)&A[(size_t)(rb + lr_) * K + k0 + lk]
                                    : float4{0.f, 0.f, 0.f, 0.f};
        if (bnsum) {
            int c0 = k0 + lk;
            av.x = fmaf(av.x, ssc[c0 + 0], ssh[c0 + 0]); av.x = fmaxf(av.x, 0.01f * av.x);
            av.y = fmaf(av.y, ssc[c0 + 1], ssh[c0 + 1]); av.y = fmaxf(av.y, 0.01f * av.y);
            av.z = fmaf(av.z, ssc[c0 + 2], ssh[c0 + 2]); av.z = fmaxf(av.z, 0.01f * av.z);
            av.w = fmaf(av.w, ssc[c0 + 3], ssh[c0 + 3]); av.w = fmaxf(av.w, 0.01f * av.w);
        }
        return av;
    };

    // prologue: stage tile 0
    float4 av = loadA(0);
    float4 bv = *(const float4*)&Bg[(size_t)bk * HDV + bc];
    As[0][lk + 0][lr_] = av.x; As[0][lk + 1][lr_] = av.y; As[0][lk + 2][lr_] = av.z; As[0][lk + 3][lr_] = av.w;
    *(float4*)&Bs[0][bk][bc] = bv;
    __syncthreads();

    float acc[8][8] = {};
    int cur = 0;
    for (int k0 = 0; k0 < K; k0 += 8) {
        bool more = (k0 + 8) < K;
        if (more) {   // issue next tile's loads; latency hides under compute below
            av = loadA(k0 + 8);
            bv = *(const float4*)&Bg[(size_t)(k0 + 8 + bk) * HDV + bc];
        }
        #pragma unroll
        for (int kk = 0; kk < 8; ++kk) {
            float a8[8], b8[8];
            *(float4*)&a8[0] = *(const float4*)&As[cur][kk][ty * 8];
            *(float4*)&a8[4] = *(const float4*)&As[cur][kk][ty * 8 + 4];
            *(float4*)&b8[0] = *(const float4*)&Bs[cur][kk][tx * 8];
            *(float4*)&b8[4] = *(const float4*)&Bs[cur][kk][tx * 8 + 4];
            #pragma unroll
            for (int ii = 0; ii < 8; ++ii)
                #pragma unroll
                for (int jj = 0; jj < 8; ++jj)
                    acc[ii][jj] = fmaf(a8[ii], b8[jj], acc[ii][jj]);
        }
        if (more) {
            int nxt = cur ^ 1;
            As[nxt][lk + 0][lr_] = av.x; As[nxt][lk + 1][lr_] = av.y;
            As[nxt][lk + 2][lr_] = av.z; As[nxt][lk + 3][lr_] = av.w;
            *(float4*)&Bs[nxt][bk][bc] = bv;
            __syncthreads();
            cur = nxt;
        }
    }
    if (blockIdx.y == 0) {   // XL: fp16 output
        #pragma unroll
        for (int ii = 0; ii < 8; ++ii) {
            int row = rb + ty * 8 + ii;
            if (row < NN) {
                __half2 h4[4];
                #pragma unroll
                for (int jj = 0; jj < 4; ++jj)
                    h4[jj] = __half2{__float2half_rn(acc[ii][2 * jj]), __float2half_rn(acc[ii][2 * jj + 1])};
                *(__half2*)&XLh[(size_t)row * HDV + tx * 8 + 0] = h4[0];
                *(__half2*)&XLh[(size_t)row * HDV + tx * 8 + 2] = h4[1];
                *(__half2*)&XLh[(size_t)row * HDV + tx * 8 + 4] = h4[2];
                *(__half2*)&XLh[(size_t)row * HDV + tx * 8 + 6] = h4[3];
            }
        }
    } else {                 // XR: fp32 output
        #pragma unroll
        for (int ii = 0; ii < 8; ++ii) {
            int row = rb + ty * 8 + ii;
            if (row < NN) {
                float4 v0 = {acc[ii][0], acc[ii][1], acc[ii][2], acc[ii][3]};
                float4 v1 = {acc[ii][4], acc[ii][5], acc[ii][6], acc[ii][7]};
                *(float4*)&XR[(size_t)row * HDV + tx * 8] = v0;
                *(float4*)&XR[(size_t)row * HDV + tx * 8 + 4] = v1;
            }
        }
    }
}

// ---------------- GATv2 per-node softmax aggregation ----------------
// one wave per node; lane L owns positions 2L,2L+1 = channels (L, 64+L) packed as float2.
// XL is fp16 (halved gather traffic); self-loop handled LAST via running ee-sum:
//   ee_self = mean_j(ea_j) @ we = mean_j(ea_j @ we) = eesum / deg   (exact, linear)
__global__ __launch_bounds__(256) void k_gat(const __half* __restrict__ XLh, const float* __restrict__ XR,
                                             const int* __restrict__ rowptr, const int* __restrict__ csr_src,
                                             const float* __restrict__ csr_ea,
                                             const float* __restrict__ we, const float* __restrict__ att,
                                             const float* __restrict__ cb, float* __restrict__ hpre) {
    int t = threadIdx.x;
    int L = t & 63;
    int d = __builtin_amdgcn_readfirstlane(blockIdx.x * 4 + (t >> 6));
    v2f rwe0[DEV / 2], rwe1[DEV / 2];   // k-pairs per head: 32 VGPRs
    #pragma unroll
    for (int j = 0; j < DEV / 2; ++j) {
        rwe0[j] = v2f{we[(2 * j) * HDV + L],      we[(2 * j + 1) * HDV + L]};
        rwe1[j] = v2f{we[(2 * j) * HDV + 64 + L], we[(2 * j + 1) * HDV + 64 + L]};
    }
    const float LOG2E = 1.4426950408889634f;
    float attv0 = att[L] * LOG2E, attv1 = att[64 + L] * LOG2E;
    v2f xr = *(const v2f*)&XR[(size_t)d * HDV + 2 * L];
    int istart = rowptr[d];
    int iend = rowptr[d + 1] - 1;           // real edges only; last slot = self-loop
    int deg = iend - istart;
    v2f Da = {0.f, 0.f}, Db = {0.f, 0.f}, Aa = {0.f, 0.f}, Ab = {0.f, 0.f};
    v2f eesum = {0.f, 0.f};

    auto body = [&](int i, v2f& Dk, v2f& Ak) {
        int sx = csr_src[i];                          // s_load, linear
        const v2f* eap = (const v2f*)(csr_ea + (size_t)i * DEV);  // uniform pairs, linear
        unsigned off = ((unsigned)sx << 8) + ((unsigned)L << 2);  // fp16 row = 256 B
        __half2 xlh = *(const __half2*)((const char*)XLh + off);  // one dword gather
        v2f xl = {__half2float(xlh.x), __half2float(xlh.y)};
        v2f e0 = {0.f, 0.f}, e1 = {0.f, 0.f};
        #pragma unroll
        for (int j = 0; j < DEV / 2; ++j) {
            v2f ea2 = eap[j];
            e0 = __builtin_elementwise_fma(ea2, rwe0[j], e0);   // v_pk_fma_f32
            e1 = __builtin_elementwise_fma(ea2, rwe1[j], e1);
        }
        v2f eev = {e0.x + e0.y, e1.x + e1.y};
        eesum += eev;
        v2f m = xl + xr + eev;
        v2f lr = __builtin_elementwise_max(m, m * 0.2f);   // leaky_relu(0.2)
        float c0 = wave_sum64(lr.x * attv0);
        float c1 = wave_sum64(lr.y * attv1);
        v2f e = {__builtin_amdgcn_exp2f(c0), __builtin_amdgcn_exp2f(c1)};
        Dk += e;
        Ak = __builtin_elementwise_fma(e, xl, Ak);
    };

    int i = istart;
    if (deg & 1) { body(i, Da, Aa); ++i; }
    for (; i < iend; i += 2) {
        body(i,     Da, Aa);
        body(i + 1, Db, Ab);
    }
    {   // self-loop: xl = own row, ee = mean of edge ee's (0 if deg==0)
        __half2 xlh = *(const __half2*)&XLh[(size_t)d * HDV + 2 * L];
        v2f xls = {__half2float(xlh.x), __half2float(xlh.y)};
        v2f eeself = eesum * (1.0f / (float)max(deg, 1));
        v2f m = xls + xr + eeself;
        v2f lr = __builtin_elementwise_max(m, m * 0.2f);
        float c0 = wave_sum64(lr.x * attv0);
        float c1 = wave_sum64(lr.y * attv1);
        v2f e = {__builtin_amdgcn_exp2f(c0), __builtin_amdgcn_exp2f(c1)};
        Da += e;
        Aa = __builtin_elementwise_fma(e, xls, Aa);
    }
    v2f D = Da + Db;
    v2f A = Aa + Ab;
    v2f h = A / (D + 1e-16f) + v2f{cb[L], cb[64 + L]};
    *(v2f*)&hpre[(size_t)d * HDV + 2 * L] = h;
}

// ---------------- BatchNorm stats (position-indexed, fp32 partials) ----------------

__global__ __launch_bounds__(256) void k_bn_stats(const float* __restrict__ hpre,
                                                  double* __restrict__ bnsum, double* __restrict__ bnsumsq) {
    int c2 = (threadIdx.x & 63) * 2;
    int rg = threadIdx.x >> 6;          // 0..3
    int r0 = blockIdx.x * 250;
    v2f s = {0.f, 0.f}, q = {0.f, 0.f};
    for (int r = r0 + rg; r < r0 + 250; r += 4) {
        v2f v = *(const v2f*)&hpre[(size_t)r * HDV + c2];
        s += v;
        q = __builtin_elementwise_fma(v, v, q);
    }
    __shared__ v2f ls[256], lq[256];
    ls[threadIdx.x] = s; lq[threadIdx.x] = q;
    __syncthreads();
    if (rg == 0) {
        int b = threadIdx.x;
        s = ls[b] + ls[b + 64] + ls[b + 128] + ls[b + 192];
        q = lq[b] + lq[b + 64] + lq[b + 128] + lq[b + 192];
        atomicAdd(&bnsum[c2],     (double)s.x);
        atomicAdd(&bnsum[c2 + 1], (double)s.y);
        atomicAdd(&bnsumsq[c2],     (double)q.x);
        atomicAdd(&bnsumsq[c2 + 1], (double)q.y);
    }
}

// ---------------- pooling + MLP ----------------

// grid (NG, PSPLIT): partial sums with layer-3 BN+leaky fused; atomic add into zeroed pooled_sum
__global__ __launch_bounds__(256) void k_pool2(const float* __restrict__ hpre, const int* __restrict__ gstart,
                                               const double* __restrict__ bnsum, const double* __restrict__ bnsumsq,
                                               const float* __restrict__ g, const float* __restrict__ bb,
                                               float* __restrict__ pooled_sum) {
    __shared__ float ssc[HDV], ssh[HDV];
    int t = threadIdx.x;
    if (t < HDV) {
        int cc = chan_of_pos(t);
        double mu = bnsum[t] * (1.0 / NN);
        double var = bnsumsq[t] * (1.0 / NN) - mu * mu;
        double inv = rsqrt(var + 1e-5);
        float sc = (float)(inv * (double)g[cc]);
        ssc[t] = sc;
        ssh[t] = bb[cc] - (float)mu * sc;
    }
    __syncthreads();
    int gr = blockIdx.x, slice = blockIdx.y;
    int s = gstart[gr], e = gstart[gr + 1];
    int c = t & 127, half = t >> 7;
    float sc = ssc[c], sh = ssh[c];
    float acc = 0.f;
    for (int r = s + slice * 2 + half; r < e; r += PSPLIT * 2) {
        float v = fmaf(hpre[(size_t)r * HDV + c], sc, sh);
        acc += fmaxf(v, 0.01f * v);
    }
    __shared__ float ls[256];
    ls[t] = acc;
    __syncthreads();
    if (half == 0) atomicAdd(&pooled_sum[gr * HDV + c], acc + ls[t + 128]);
}

__global__ __launch_bounds__(512) void k_mlp(const float* __restrict__ pooled_sum, const int* __restrict__ gstart,
                                             const float* __restrict__ fc1w, const float* __restrict__ fc1b,
                                             const float* __restrict__ fc2w, const float* __restrict__ fc2b,
                                             float* __restrict__ out) {
    __shared__ float pl[NG * HDV];   // 32 KB (positional)
    __shared__ float hh[NG * 64];    // 16 KB
    int t = threadIdx.x;
    for (int i = t; i < NG * HDV; i += 512) {
        int gr = i >> 7;
        float cnt = (float)max(gstart[gr + 1] - gstart[gr], 1);
        pl[i] = pooled_sum[i] / cnt;
    }
    __syncthreads();
    for (int i = t; i < NG * 64; i += 512) {
        int gr = i >> 6, c = i & 63;
        float s = fc1b[c];
        for (int p = 0; p < HDV; ++p)
            s += pl[gr * HDV + p] * fc1w[chan_of_pos(p) * 64 + c];
        hh[i] = s > 0.f ? s : 0.f;
    }
    __syncthreads();
    if (t < NG) {
        float s = fc2b[0];
        for (int k = 0; k < 64; ++k) s += hh[t * 64 + k] * fc2w[k];
        out[t] = s;
    }
}

// ---------------- launch ----------------

extern "C" void kernel_launch(void* const* d_in, const int* in_sizes, int n_in,
                              void* d_out, int out_size, void* d_ws, size_t ws_size,
                              hipStream_t stream) {
    const float* x = (const float*)d_in[0];
    const int* ei = (const int*)d_in[1];
    const int* src = ei;
    const int* dst = ei + NE;
    const float* ea = (const float*)d_in[2];
    const int* batch = (const int*)d_in[3];
    const float* fc1w = (const float*)d_in[25];
    const float* fc1b = (const float*)d_in[26];
    const float* fc2w = (const float*)d_in[27];
    const float* fc2b = (const float*)d_in[28];
    float* out = (float*)d_out;

    char* ws = (char*)d_ws;
    size_t off = 0;
    auto alloc = [&](size_t bytes) -> void* {
        void* p = ws + off;
        off = (off + bytes + 255) & ~(size_t)255;
        return p;
    };

    // zero region (memset every launch)
    int* cnt = (int*)alloc(NN * 4);
    double* bnsum = (double*)alloc(3 * HDV * 8);
    double* bnsumsq = (double*)alloc(3 * HDV * 8);
    float* pooled_sum = (float*)alloc(NG * HDV * 4);
    size_t zero_bytes = off;

    int* rowptr = (int*)alloc((NN + 1) * 4);
    int* cursor = (int*)alloc(NN * 4);
    int* gstart = (int*)alloc((NG + 1) * 4);
    int* bsum = (int*)alloc(NSB * 4);
    int* boff = (int*)alloc(256 * 4);
    float* wlp = (float*)alloc(3 * HDV * HDV * 4);
    float* wrp = (float*)alloc(3 * HDV * HDV * 4);
    int* csr_src = (int*)alloc(((size_t)EF + 16) * 4);
    float* csr_ea = (float*)alloc(((size_t)EF * DEV + 64) * 4);
    __half* XLh = (__half*)alloc((size_t)NN * HDV * 2);
    float* XRb = (float*)alloc((size_t)NN * HDV * 4);
    float* hpre = (float*)alloc((size_t)NN * HDV * 4);
    (void)ws_size; (void)in_sizes; (void)n_in; (void)out_size;

    hipMemsetAsync(d_ws, 0, zero_bytes, stream);

    k_count<<<(NE + 255) / 256, 256, 0, stream>>>(dst, cnt);
    k_scan_a<<<NSB, 256, 0, stream>>>(cnt, bsum);
    k_scan_b<<<1, 256, 0, stream>>>(bsum, boff);
    k_scan_c<<<NSB, 256, 0, stream>>>(cnt, boff, rowptr, cursor);
    k_fill<<<(NE + 255) / 256, 256, 0, stream>>>(src, dst, ea, cursor, csr_src, csr_ea);
    k_wperm_all<<<(3 * HDV * HDV + 255) / 256 + 1, 256, 0, stream>>>(
        (const float*)d_in[4], (const float*)d_in[5],
        (const float*)d_in[11], (const float*)d_in[12],
        (const float*)d_in[18], (const float*)d_in[19], wlp, wrp, batch, gstart);

    const float* actp = x;
    int K = DINV;
    for (int L = 0; L < 3; ++L) {
        const float* we = (const float*)d_in[4 + 7 * L + 2];
        const float* a  = (const float*)d_in[4 + 7 * L + 3];
        const float* cb = (const float*)d_in[4 + 7 * L + 4];

        const double* bs  = (L == 0) ? nullptr : bnsum + (size_t)(L - 1) * HDV;
        const double* bsq = (L == 0) ? nullptr : bnsumsq + (size_t)(L - 1) * HDV;
        const float* gg   = (L == 0) ? nullptr : (const float*)d_in[4 + 7 * (L - 1) + 5];
        const float* bbp  = (L == 0) ? nullptr : (const float*)d_in[4 + 7 * (L - 1) + 6];

        k_gemm<<<dim3((NN + 127) / 128, 2), 256, 0, stream>>>(
            actp, K, wlp + (size_t)L * HDV * HDV, wrp + (size_t)L * HDV * HDV,
            XLh, XRb, bs, bsq, gg, bbp);
        k_gat<<<NN / 4, 256, 0, stream>>>(XLh, XRb, rowptr, csr_src, csr_ea, we, a, cb, hpre);
        k_bn_stats<<<160, 256, 0, stream>>>(hpre, bnsum + (size_t)L * HDV, bnsumsq + (size_t)L * HDV);
        actp = hpre;
        K = HDV;
    }

    k_pool2<<<dim3(NG, PSPLIT), 256, 0, stream>>>(
        hpre, gstart, bnsum + 2 * HDV, bnsumsq + 2 * HDV,
        (const float*)d_in[4 + 7 * 2 + 5], (const float*)d_in[4 + 7 * 2 + 6], pooled_sum);
    k_mlp<<<1, 512, 0, stream>>>(pooled_sum, gstart, fc1w, fc1b, fc2w, fc2b, out);
}

// Round 12
// 494.794 us; speedup vs baseline: 1.2450x; 1.0526x over previous
//
#include <hip/hip_runtime.h>
#include <hip/hip_fp16.h>
#include <math.h>

#define NN 40000
#define NE 640000
#define NG 64
#define DINV 64
#define HDV 128
#define DEV 16
#define EF (NE + NN)
#define PSPLIT 16
#define NSB ((NN + 255) / 256)   // 157 scan blocks

typedef float v2f __attribute__((ext_vector_type(2)));

// position p <-> channel: lane L (half-wave h=L>>5) owns positions 4*(L&31)+2*h+{0,1}
// = channels h*64 + 2*(L&31) + {0,1}.  chan(p) = 2*(p>>2) + (p&1) + 64*((p>>1)&1)
__device__ __forceinline__ int chan_of_pos(int p) { return ((p >> 2) << 1) + (p & 1) + (((p >> 1) & 1) << 6); }

// ---------------- DPP half-wave sums: lane31 = sum(l 0..31), lane63 = sum(32..63) ----------------
template <int CTRL>
__device__ __forceinline__ float dpp_mov_f(float x) {
    return __builtin_bit_cast(float,
        __builtin_amdgcn_update_dpp(0, __builtin_bit_cast(int, x), CTRL, 0xf, 0xf, true));
}
__device__ __forceinline__ v2f half_sums(float x) {
    x += dpp_mov_f<0x111>(x);   // row_shr:1
    x += dpp_mov_f<0x112>(x);   // row_shr:2
    x += dpp_mov_f<0x114>(x);   // row_shr:4
    x += dpp_mov_f<0x118>(x);   // row_shr:8
    x += dpp_mov_f<0x142>(x);   // row_bcast:15 -> lane31/lane63 hold half sums
    float s0 = __builtin_bit_cast(float, __builtin_amdgcn_readlane(__builtin_bit_cast(int, x), 31));
    float s1 = __builtin_bit_cast(float, __builtin_amdgcn_readlane(__builtin_bit_cast(int, x), 63));
    return v2f{s0, s1};
}

// ---------------- CSR construction ----------------

__global__ void k_count(const int* __restrict__ dst, int* __restrict__ cnt) {
    int e = blockIdx.x * 256 + threadIdx.x;
    if (e < NE) atomicAdd(&cnt[dst[e]], 1);
}

// hierarchical coalesced scan of (cnt[i]+1): a) block sums, b) scan sums, c) final
__global__ __launch_bounds__(256) void k_scan_a(const int* __restrict__ cnt, int* __restrict__ bsum) {
    int i = blockIdx.x * 256 + threadIdx.x;
    int v = (i < NN) ? cnt[i] + 1 : 0;
    __shared__ int s[256];
    s[threadIdx.x] = v;
    __syncthreads();
    for (int off = 128; off > 0; off >>= 1) {
        if (threadIdx.x < off) s[threadIdx.x] += s[threadIdx.x + off];
        __syncthreads();
    }
    if (threadIdx.x == 0) bsum[blockIdx.x] = s[0];
}

__global__ __launch_bounds__(256) void k_scan_b(const int* __restrict__ bsum, int* __restrict__ boff) {
    int t = threadIdx.x;
    int v = (t < NSB) ? bsum[t] : 0;
    __shared__ int s[256];
    s[t] = v;
    __syncthreads();
    for (int off = 1; off < 256; off <<= 1) {
        int add = (t >= off) ? s[t - off] : 0;
        __syncthreads();
        s[t] += add;
        __syncthreads();
    }
    boff[t] = s[t] - v;   // exclusive
}

__global__ __launch_bounds__(256) void k_scan_c(const int* __restrict__ cnt, const int* __restrict__ boff,
                                                int* __restrict__ rowptr, int* __restrict__ cursor) {
    int i = blockIdx.x * 256 + threadIdx.x;
    int t = threadIdx.x;
    int v = (i < NN) ? cnt[i] + 1 : 0;
    __shared__ int s[256];
    s[t] = v;
    __syncthreads();
    for (int off = 1; off < 256; off <<= 1) {
        int add = (t >= off) ? s[t - off] : 0;
        __syncthreads();
        s[t] += add;
        __syncthreads();
    }
    int excl = boff[blockIdx.x] + s[t] - v;
    if (i < NN) {
        rowptr[i] = excl;
        cursor[i] = excl;
        if (i == NN - 1) rowptr[NN] = excl + v;   // = EF
    }
}

// fill CSR adjacency AND edge attrs in CSR order (linear s_load stream for k_gat)
__global__ void k_fill(const int* __restrict__ src, const int* __restrict__ dst,
                       const float* __restrict__ edge_attr,
                       int* __restrict__ cursor, int* __restrict__ csr_src, float* __restrict__ csr_ea) {
    int e = blockIdx.x * 256 + threadIdx.x;
    if (e < NE) {
        int d = dst[e];
        int p = atomicAdd(&cursor[d], 1);
        csr_src[p] = src[e];
        const float4* s4 = (const float4*)&edge_attr[(size_t)e * DEV];
        float4* d4 = (float4*)&csr_ea[(size_t)p * DEV];
        d4[0] = s4[0]; d4[1] = s4[1]; d4[2] = s4[2]; d4[3] = s4[3];
    }
}

// ---------------- weight permutation (all 3 layers) + graph bounds, one launch ----------------
__global__ void k_wperm_all(const float* __restrict__ w1l, const float* __restrict__ w1r,
                            const float* __restrict__ w2l, const float* __restrict__ w2r,
                            const float* __restrict__ w3l, const float* __restrict__ w3r,
                            float* __restrict__ wlp, float* __restrict__ wrp,
                            const int* __restrict__ batch, int* __restrict__ gstart) {
    int t = threadIdx.x;
    if (blockIdx.x == gridDim.x - 1) {   // graph boundaries via binary search (batch sorted)
        int g = t;
        if (g > NG) return;
        int lo = 0, hi = NN;
        while (lo < hi) {
            int mid = (lo + hi) >> 1;
            if (batch[mid] < g) lo = mid + 1; else hi = mid;
        }
        gstart[g] = lo;
        return;
    }
    int i = blockIdx.x * 256 + t;
    if (i >= 3 * HDV * HDV) return;
    int layer = i / (HDV * HDV);
    int r = i - layer * HDV * HDV;
    int p = r & 127, kp = r >> 7;
    int K = (layer == 0) ? DINV : HDV;
    if (kp >= K) return;
    int kr = (layer == 0) ? kp : chan_of_pos(kp);   // rows positional for layers 2,3
    int cc = chan_of_pos(p);
    const float* wl = (layer == 0) ? w1l : (layer == 1) ? w2l : w3l;
    const float* wr = (layer == 0) ? w1r : (layer == 1) ? w2r : w3r;
    wlp[i] = wl[kr * HDV + cc];
    wrp[i] = wr[kr * HDV + cc];
}

// ---------------- dense transforms: XL = A@Wl (fp16 out), XR = A@Wr (fp32 out) ----------------
__global__ __launch_bounds__(256) void k_gemm(const float* __restrict__ A, int K,
                                              const float* __restrict__ Wl, const float* __restrict__ Wr,
                                              __half* __restrict__ XLh, float* __restrict__ XR,
                                              const double* __restrict__ bnsum, const double* __restrict__ bnsumsq,
                                              const float* __restrict__ g, const float* __restrict__ bb) {
    __shared__ float As[2][8][128];
    __shared__ float Bs[2][8][128];
    __shared__ float ssc[HDV], ssh[HDV];
    int t = threadIdx.x;
    if (bnsum && t < HDV) {   // BN scale/shift of previous layer (positional index t)
        int c = chan_of_pos(t);
        double mu = bnsum[t] * (1.0 / NN);
        double var = bnsumsq[t] * (1.0 / NN) - mu * mu;
        double inv = rsqrt(var + 1e-5);
        float sc = (float)(inv * (double)g[c]);
        ssc[t] = sc;
        ssh[t] = bb[c] - (float)mu * sc;
    }
    __syncthreads();
    int rb = blockIdx.x * 128;
    const float* __restrict__ Bg = blockIdx.y ? Wr : Wl;
    int tx = t & 15, ty = t >> 4;
    int lr_ = t >> 1, lk = (t & 1) * 4;
    int bk = t >> 5, bc = (t & 31) * 4;

    auto loadA = [&](int k0) -> float4 {
        float4 av = (rb + lr_ < NN) ? *(const float4*)&A[(size_t)(rb + lr_) * K + k0 + lk]
                                    : float4{0.f, 0.f, 0.f, 0.f};
        if (bnsum) {
            int c0 = k0 + lk;
            av.x = fmaf(av.x, ssc[c0 + 0], ssh[c0 + 0]); av.x = fmaxf(av.x, 0.01f * av.x);
            av.y = fmaf(av.y, ssc[c0 + 1], ssh[c0 + 1]); av.y = fmaxf(av.y, 0.01f * av.y);
            av.z = fmaf(av.z, ssc[c0 + 2], ssh[c0 + 2]); av.z = fmaxf(av.z, 0.01f * av.z);
            av.w = fmaf(av.w, ssc[c0 + 3], ssh[c0 + 3]); av.w = fmaxf(av.w, 0.01f * av.w);
        }
        return av;
    };

    float4 av = loadA(0);
    float4 bv = *(const float4*)&Bg[(size_t)bk * HDV + bc];
    As[0][lk + 0][lr_] = av.x; As[0][lk + 1][lr_] = av.y; As[0][lk + 2][lr_] = av.z; As[0][lk + 3][lr_] = av.w;
    *(float4*)&Bs[0][bk][bc] = bv;
    __syncthreads();

    float acc[8][8] = {};
    int cur = 0;
    for (int k0 = 0; k0 < K; k0 += 8) {
        bool more = (k0 + 8) < K;
        if (more) {
            av = loadA(k0 + 8);
            bv = *(const float4*)&Bg[(size_t)(k0 + 8 + bk) * HDV + bc];
        }
        #pragma unroll
        for (int kk = 0; kk < 8; ++kk) {
            float a8[8], b8[8];
            *(float4*)&a8[0] = *(const float4*)&As[cur][kk][ty * 8];
            *(float4*)&a8[4] = *(const float4*)&As[cur][kk][ty * 8 + 4];
            *(float4*)&b8[0] = *(const float4*)&Bs[cur][kk][tx * 8];
            *(float4*)&b8[4] = *(const float4*)&Bs[cur][kk][tx * 8 + 4];
            #pragma unroll
            for (int ii = 0; ii < 8; ++ii)
                #pragma unroll
                for (int jj = 0; jj < 8; ++jj)
                    acc[ii][jj] = fmaf(a8[ii], b8[jj], acc[ii][jj]);
        }
        if (more) {
            int nxt = cur ^ 1;
            As[nxt][lk + 0][lr_] = av.x; As[nxt][lk + 1][lr_] = av.y;
            As[nxt][lk + 2][lr_] = av.z; As[nxt][lk + 3][lr_] = av.w;
            *(float4*)&Bs[nxt][bk][bc] = bv;
            __syncthreads();
            cur = nxt;
        }
    }
    if (blockIdx.y == 0) {   // XL: fp16 output
        #pragma unroll
        for (int ii = 0; ii < 8; ++ii) {
            int row = rb + ty * 8 + ii;
            if (row < NN) {
                __half2 h4[4];
                #pragma unroll
                for (int jj = 0; jj < 4; ++jj)
                    h4[jj] = __half2{__float2half_rn(acc[ii][2 * jj]), __float2half_rn(acc[ii][2 * jj + 1])};
                *(__half2*)&XLh[(size_t)row * HDV + tx * 8 + 0] = h4[0];
                *(__half2*)&XLh[(size_t)row * HDV + tx * 8 + 2] = h4[1];
                *(__half2*)&XLh[(size_t)row * HDV + tx * 8 + 4] = h4[2];
                *(__half2*)&XLh[(size_t)row * HDV + tx * 8 + 6] = h4[3];
            }
        }
    } else {                 // XR: fp32 output
        #pragma unroll
        for (int ii = 0; ii < 8; ++ii) {
            int row = rb + ty * 8 + ii;
            if (row < NN) {
                float4 v0 = {acc[ii][0], acc[ii][1], acc[ii][2], acc[ii][3]};
                float4 v1 = {acc[ii][4], acc[ii][5], acc[ii][6], acc[ii][7]};
                *(float4*)&XR[(size_t)row * HDV + tx * 8] = v0;
                *(float4*)&XR[(size_t)row * HDV + tx * 8 + 4] = v1;
            }
        }
    }
}

// ---------------- GATv2 per-node softmax aggregation ----------------
// one wave per node; half-wave h owns head h: lane L holds channels h*64+2*(L&31)+{0,1}
// (positions 4*(L&31)+2*h+{0,1}).  One 5-step DPP chain reduces BOTH heads per edge.
__global__ __launch_bounds__(256) void k_gat(const __half* __restrict__ XLh, const float* __restrict__ XR,
                                             const int* __restrict__ rowptr, const int* __restrict__ csr_src,
                                             const float* __restrict__ csr_ea,
                                             const float* __restrict__ we, const float* __restrict__ att,
                                             const float* __restrict__ cb, float* __restrict__ hpre) {
    int t = threadIdx.x;
    int L = t & 63;
    int l5 = L & 31, hh = L >> 5;
    int c0 = hh * 64 + 2 * l5;          // channel pair (c0, c0+1), same head
    int poff = 4 * l5 + 2 * hh;         // position pair (poff, poff+1)
    int d = __builtin_amdgcn_readfirstlane(blockIdx.x * 4 + (t >> 6));
    v2f rwe0[DEV / 2], rwe1[DEV / 2];   // k-pairs per slot: 32 VGPRs
    #pragma unroll
    for (int j = 0; j < DEV / 2; ++j) {
        rwe0[j] = v2f{we[(2 * j) * HDV + c0],     we[(2 * j + 1) * HDV + c0]};
        rwe1[j] = v2f{we[(2 * j) * HDV + c0 + 1], we[(2 * j + 1) * HDV + c0 + 1]};
    }
    const float LOG2E = 1.4426950408889634f;
    v2f attv = {att[c0] * LOG2E, att[c0 + 1] * LOG2E};
    v2f xr = *(const v2f*)&XR[(size_t)d * HDV + poff];
    int istart = rowptr[d];
    int iend = rowptr[d + 1] - 1;       // real edges only; last slot = self-loop
    int deg = iend - istart;
    float Da = 0.f, Db = 0.f;           // own head's denominator
    v2f Aa = {0.f, 0.f}, Ab = {0.f, 0.f};
    v2f eesum = {0.f, 0.f};
    unsigned xoff = ((unsigned)poff << 1);   // fp16 byte offset within row

    auto body = [&](int i, float& Dk, v2f& Ak) {
        int sx = csr_src[i];                          // s_load, linear
        const v2f* eap = (const v2f*)(csr_ea + (size_t)i * DEV);  // uniform pairs, linear
        unsigned off = ((unsigned)sx << 8) + xoff;    // fp16 row = 256 B
        __half2 xlh = *(const __half2*)((const char*)XLh + off);  // one dword gather
        v2f xl = {__half2float(xlh.x), __half2float(xlh.y)};
        v2f e0 = {0.f, 0.f}, e1 = {0.f, 0.f};
        #pragma unroll
        for (int j = 0; j < DEV / 2; ++j) {
            v2f ea2 = eap[j];
            e0 = __builtin_elementwise_fma(ea2, rwe0[j], e0);   // v_pk_fma_f32
            e1 = __builtin_elementwise_fma(ea2, rwe1[j], e1);
        }
        v2f eev = {e0.x + e0.y, e1.x + e1.y};
        eesum += eev;
        v2f m = xl + xr + eev;
        v2f lr = __builtin_elementwise_max(m, m * 0.2f);   // leaky_relu(0.2)
        float cl = fmaf(lr.y, attv.y, lr.x * attv.x);      // lane-local pair fold
        v2f s = half_sums(cl);                             // s.x = head0 score, s.y = head1
        float es0 = __builtin_amdgcn_exp2f(s.x);
        float es1 = __builtin_amdgcn_exp2f(s.y);
        float es = hh ? es1 : es0;                         // own head's weight
        Dk += es;
        Ak = __builtin_elementwise_fma(v2f{es, es}, xl, Ak);
    };

    int i = istart;
    if (deg & 1) { body(i, Da, Aa); ++i; }
    for (; i < iend; i += 2) {
        body(i,     Da, Aa);
        body(i + 1, Db, Ab);
    }
    {   // self-loop: xl = own row, ee = mean of edge ee's (0 if deg==0)
        __half2 xlh = *(const __half2*)&XLh[(size_t)d * HDV + poff];
        v2f xls = {__half2float(xlh.x), __half2float(xlh.y)};
        v2f eeself = eesum * (1.0f / (float)max(deg, 1));
        v2f m = xls + xr + eeself;
        v2f lr = __builtin_elementwise_max(m, m * 0.2f);
        float cl = fmaf(lr.y, attv.y, lr.x * attv.x);
        v2f s = half_sums(cl);
        float es0 = __builtin_amdgcn_exp2f(s.x);
        float es1 = __builtin_amdgcn_exp2f(s.y);
        float es = hh ? es1 : es0;
        Da += es;
        Aa = __builtin_elementwise_fma(v2f{es, es}, xls, Aa);
    }
    float D = Da + Db;
    v2f A = Aa + Ab;
    float dinv = 1.0f / (D + 1e-16f);
    v2f h = A * v2f{dinv, dinv} + v2f{cb[c0], cb[c0 + 1]};
    *(v2f*)&hpre[(size_t)d * HDV + poff] = h;
}

// ---------------- BatchNorm stats (position-indexed, fp32 partials) ----------------

__global__ __launch_bounds__(256) void k_bn_stats(const float* __restrict__ hpre,
                                                  double* __restrict__ bnsum, double* __restrict__ bnsumsq) {
    int c2 = (threadIdx.x & 63) * 2;
    int rg = threadIdx.x >> 6;          // 0..3
    int r0 = blockIdx.x * 250;
    v2f s = {0.f, 0.f}, q = {0.f, 0.f};
    for (int r = r0 + rg; r < r0 + 250; r += 4) {
        v2f v = *(const v2f*)&hpre[(size_t)r * HDV + c2];
        s += v;
        q = __builtin_elementwise_fma(v, v, q);
    }
    __shared__ v2f ls[256], lq[256];
    ls[threadIdx.x] = s; lq[threadIdx.x] = q;
    __syncthreads();
    if (rg == 0) {
        int b = threadIdx.x;
        s = ls[b] + ls[b + 64] + ls[b + 128] + ls[b + 192];
        q = lq[b] + lq[b + 64] + lq[b + 128] + lq[b + 192];
        atomicAdd(&bnsum[c2],     (double)s.x);
        atomicAdd(&bnsum[c2 + 1], (double)s.y);
        atomicAdd(&bnsumsq[c2],     (double)q.x);
        atomicAdd(&bnsumsq[c2 + 1], (double)q.y);
    }
}

// ---------------- pooling + MLP ----------------

// grid (NG, PSPLIT): partial sums with layer-3 BN+leaky fused; atomic add into zeroed pooled_sum
__global__ __launch_bounds__(256) void k_pool2(const float* __restrict__ hpre, const int* __restrict__ gstart,
                                               const double* __restrict__ bnsum, const double* __restrict__ bnsumsq,
                                               const float* __restrict__ g, const float* __restrict__ bb,
                                               float* __restrict__ pooled_sum) {
    __shared__ float ssc[HDV], ssh[HDV];
    int t = threadIdx.x;
    if (t < HDV) {
        int cc = chan_of_pos(t);
        double mu = bnsum[t] * (1.0 / NN);
        double var = bnsumsq[t] * (1.0 / NN) - mu * mu;
        double inv = rsqrt(var + 1e-5);
        float sc = (float)(inv * (double)g[cc]);
        ssc[t] = sc;
        ssh[t] = bb[cc] - (float)mu * sc;
    }
    __syncthreads();
    int gr = blockIdx.x, slice = blockIdx.y;
    int s = gstart[gr], e = gstart[gr + 1];
    int c = t & 127, half = t >> 7;
    float sc = ssc[c], sh = ssh[c];
    float acc = 0.f;
    for (int r = s + slice * 2 + half; r < e; r += PSPLIT * 2) {
        float v = fmaf(hpre[(size_t)r * HDV + c], sc, sh);
        acc += fmaxf(v, 0.01f * v);
    }
    __shared__ float ls[256];
    ls[t] = acc;
    __syncthreads();
    if (half == 0) atomicAdd(&pooled_sum[gr * HDV + c], acc + ls[t + 128]);
}

__global__ __launch_bounds__(512) void k_mlp(const float* __restrict__ pooled_sum, const int* __restrict__ gstart,
                                             const float* __restrict__ fc1w, const float* __restrict__ fc1b,
                                             const float* __restrict__ fc2w, const float* __restrict__ fc2b,
                                             float* __restrict__ out) {
    __shared__ float pl[NG * HDV];   // 32 KB (positional)
    __shared__ float hh[NG * 64];    // 16 KB
    int t = threadIdx.x;
    for (int i = t; i < NG * HDV; i += 512) {
        int gr = i >> 7;
        float cnt = (float)max(gstart[gr + 1] - gstart[gr], 1);
        pl[i] = pooled_sum[i] / cnt;
    }
    __syncthreads();
    for (int i = t; i < NG * 64; i += 512) {
        int gr = i >> 6, c = i & 63;
        float s = fc1b[c];
        for (int p = 0; p < HDV; ++p)
            s += pl[gr * HDV + p] * fc1w[chan_of_pos(p) * 64 + c];
        hh[i] = s > 0.f ? s : 0.f;
    }
    __syncthreads();
    if (t < NG) {
        float s = fc2b[0];
        for (int k = 0; k < 64; ++k) s += hh[t * 64 + k] * fc2w[k];
        out[t] = s;
    }
}

// ---------------- launch ----------------

extern "C" void kernel_launch(void* const* d_in, const int* in_sizes, int n_in,
                              void* d_out, int out_size, void* d_ws, size_t ws_size,
                              hipStream_t stream) {
    const float* x = (const float*)d_in[0];
    const int* ei = (const int*)d_in[1];
    const int* src = ei;
    const int* dst = ei + NE;
    const float* ea = (const float*)d_in[2];
    const int* batch = (const int*)d_in[3];
    const float* fc1w = (const float*)d_in[25];
    const float* fc1b = (const float*)d_in[26];
    const float* fc2w = (const float*)d_in[27];
    const float* fc2b = (const float*)d_in[28];
    float* out = (float*)d_out;

    char* ws = (char*)d_ws;
    size_t off = 0;
    auto alloc = [&](size_t bytes) -> void* {
        void* p = ws + off;
        off = (off + bytes + 255) & ~(size_t)255;
        return p;
    };

    // zero region (memset every launch)
    int* cnt = (int*)alloc(NN * 4);
    double* bnsum = (double*)alloc(3 * HDV * 8);
    double* bnsumsq = (double*)alloc(3 * HDV * 8);
    float* pooled_sum = (float*)alloc(NG * HDV * 4);
    size_t zero_bytes = off;

    int* rowptr = (int*)alloc((NN + 1) * 4);
    int* cursor = (int*)alloc(NN * 4);
    int* gstart = (int*)alloc((NG + 1) * 4);
    int* bsum = (int*)alloc(NSB * 4);
    int* boff = (int*)alloc(256 * 4);
    float* wlp = (float*)alloc(3 * HDV * HDV * 4);
    float* wrp = (float*)alloc(3 * HDV * HDV * 4);
    int* csr_src = (int*)alloc(((size_t)EF + 16) * 4);
    float* csr_ea = (float*)alloc(((size_t)EF * DEV + 64) * 4);
    __half* XLh = (__half*)alloc((size_t)NN * HDV * 2);
    float* XRb = (float*)alloc((size_t)NN * HDV * 4);
    float* hpre = (float*)alloc((size_t)NN * HDV * 4);
    (void)ws_size; (void)in_sizes; (void)n_in; (void)out_size;

    hipMemsetAsync(d_ws, 0, zero_bytes, stream);

    k_count<<<(NE + 255) / 256, 256, 0, stream>>>(dst, cnt);
    k_scan_a<<<NSB, 256, 0, stream>>>(cnt, bsum);
    k_scan_b<<<1, 256, 0, stream>>>(bsum, boff);
    k_scan_c<<<NSB, 256, 0, stream>>>(cnt, boff, rowptr, cursor);
    k_fill<<<(NE + 255) / 256, 256, 0, stream>>>(src, dst, ea, cursor, csr_src, csr_ea);
    k_wperm_all<<<(3 * HDV * HDV + 255) / 256 + 1, 256, 0, stream>>>(
        (const float*)d_in[4], (const float*)d_in[5],
        (const float*)d_in[11], (const float*)d_in[12],
        (const float*)d_in[18], (const float*)d_in[19], wlp, wrp, batch, gstart);

    const float* actp = x;
    int K = DINV;
    for (int L = 0; L < 3; ++L) {
        const float* we = (const float*)d_in[4 + 7 * L + 2];
        const float* a  = (const float*)d_in[4 + 7 * L + 3];
        const float* cb = (const float*)d_in[4 + 7 * L + 4];

        const double* bs  = (L == 0) ? nullptr : bnsum + (size_t)(L - 1) * HDV;
        const double* bsq = (L == 0) ? nullptr : bnsumsq + (size_t)(L - 1) * HDV;
        const float* gg   = (L == 0) ? nullptr : (const float*)d_in[4 + 7 * (L - 1) + 5];
        const float* bbp  = (L == 0) ? nullptr : (const float*)d_in[4 + 7 * (L - 1) + 6];

        k_gemm<<<dim3((NN + 127) / 128, 2), 256, 0, stream>>>(
            actp, K, wlp + (size_t)L * HDV * HDV, wrp + (size_t)L * HDV * HDV,
            XLh, XRb, bs, bsq, gg, bbp);
        k_gat<<<NN / 4, 256, 0, stream>>>(XLh, XRb, rowptr, csr_src, csr_ea, we, a, cb, hpre);
        k_bn_stats<<<160, 256, 0, stream>>>(hpre, bnsum + (size_t)L * HDV, bnsumsq + (size_t)L * HDV);
        actp = hpre;
        K = HDV;
    }

    k_pool2<<<dim3(NG, PSPLIT), 256, 0, stream>>>(
        hpre, gstart, bnsum + 2 * HDV, bnsumsq + 2 * HDV,
        (const float*)d_in[4 + 7 * 2 + 5], (const float*)d_in[4 + 7 * 2 + 6], pooled_sum);
    k_mlp<<<1, 512, 0, stream>>>(pooled_sum, gstart, fc1w, fc1b, fc2w, fc2b, out);
}